// Round 10
// baseline (211.978 us; speedup 1.0000x reference)
//
#include <hip/hip_runtime.h>

typedef float f32x4 __attribute__((ext_vector_type(4)));
typedef short bf16x8 __attribute__((ext_vector_type(8)));

__device__ __forceinline__ short f2bf(float x) {
    unsigned u = __float_as_uint(x);
    unsigned r = (u + 0x7FFFu + ((u >> 16) & 1u)) >> 16;  // RNE
    return (short)r;
}

// ---------------- prep 1: An2 = (D^-1/2 (W+I) D^-1/2)^2, written as bf16 A-fragments ----------------
__global__ void prep_an2(const float* __restrict__ tril, short* __restrict__ an2f) {
    __shared__ float Wm[64][64];
    __shared__ float An[64][64];
    __shared__ float An2[64][64];
    __shared__ float dinv[64];
    const int t = threadIdx.x;  // 256 threads
    for (int e = t; e < 4096; e += 256) {
        int i = e >> 6, j = e & 63;
        int hi = i > j ? i : j, lo = i > j ? j : i;
        Wm[i][j] = tril[hi * (hi + 1) / 2 + lo];  // symmetric rebuild
    }
    __syncthreads();
    if (t < 64) {
        float s = 0.f;
        for (int j = 0; j < 64; ++j) s += fabsf(Wm[t][j]);
        s += 1.0f;
        dinv[t] = (s > 0.f) ? 1.0f / sqrtf(s) : 0.f;
    }
    __syncthreads();
    for (int e = t; e < 4096; e += 256) {
        int i = e >> 6, j = e & 63;
        float a = Wm[i][j] + (i == j ? 1.0f : 0.0f);
        An[i][j] = dinv[i] * a * dinv[j];
    }
    __syncthreads();
    for (int e = t; e < 4096; e += 256) {
        int i = e >> 6, j = e & 63;
        float acc = 0.f;
        for (int m = 0; m < 64; ++m) acc += An[i][m] * An[m][j];
        An2[i][j] = acc;
    }
    __syncthreads();
    // A-fragment order: [mt(4)][kt(2)][lane(64)][e(8)], elem = An2[mt*16+(lane&15)][kt*32+8*(lane>>4)+e]
    for (int o = t; o < 4096; o += 256) {
        int e = o & 7, lane = (o >> 3) & 63, kt = (o >> 9) & 1, mt = o >> 10;
        int m = mt * 16 + (lane & 15);
        int k = kt * 32 + 8 * (lane >> 4) + e;
        an2f[o] = f2bf(An2[m][k]);
    }
}

// ---------------- prep 2: convW -> bf16 B-fragments [kt(8)][nt(32)][lane(64)][e(8)] ----------------
__global__ void prep_wf(const float* __restrict__ convW, short* __restrict__ wf) {
    int o = blockIdx.x * 256 + threadIdx.x;  // 131072 elements
    int e = o & 7, lane = (o >> 3) & 63, nt = (o >> 9) & 31, kt = o >> 14;
    int k = kt * 32 + 8 * (lane >> 4) + e;
    int j = nt * 16 + (lane & 15);
    wf[o] = f2bf(convW[k * 512 + j]);
}

// ---------------- main: per-batch fused hop+conv+pool+fc+log_softmax ----------------
// 512-thread blocks (8 waves), HALVED per-wave tiles to cut the register floor:
//  phase A: wave = 64n x 32c  -> acc[4][2] = 32 AGPR, bfr hoist 16 VGPR
//  phase B: wave = 64j, two sequential 32n passes -> acc[2][4] = 32 AGPR, psum 4
//  an2 fragments read transiently from LDS (no 32-reg hoist)
// True floor ~75-90 regs; launch_bounds(512,4) caps at 128 with real headroom
// (R4/R7/R8 lesson: caps below the floor spill; R9 lesson: permissive caps bloat).
// LDS 42KB/block shared by 8 waves -> 2 blocks/CU = 4 waves/SIMD (2x round 9).
__global__ __launch_bounds__(512, 4) void rgnn_main(
    const float* __restrict__ X, const short* __restrict__ an2f,
    const short* __restrict__ wf, const float* __restrict__ convb,
    const float* __restrict__ fcW, const float* __restrict__ fcb,
    float* __restrict__ out)
{
    __shared__ short xbuf[16384];    // 32KB: X[b]^T [c][m] bf16 (128B swz rows), then xs [n][c] (512B swz rows)
    __shared__ short an2lds[4096];   // 8KB: An2 bf16 A-fragments
    __shared__ float pooled[512];
    const int b = blockIdx.x;
    const int t = threadIdx.x;
    const int lane = t & 63;
    const int wid = t >> 6;          // 0..7
    const float* Xb = X + (size_t)b * (64 * 256);

    // ---- stage an2f -> LDS (512 threads x 8 shorts)
    *(bf16x8*)&an2lds[t * 8] = *(const bf16x8*)&an2f[t * 8];
    // ---- stage X[b] -> xbuf as X^T bf16: thread handles column c, rows mh*32..mh*32+31
    {
        const int c = t & 255, mh = t >> 8;
        #pragma unroll 2
        for (int m0 = 0; m0 < 32; m0 += 8) {
            bf16x8 v;
            #pragma unroll
            for (int i = 0; i < 8; ++i) v[i] = f2bf(Xb[(mh * 32 + m0 + i) * 256 + c]);
            int byte = c * 128 + (mh * 32 + m0) * 2;
            byte ^= (c & 7) << 4;
            *(bf16x8*)((char*)xbuf + byte) = v;
        }
    }
    __syncthreads();

    // ---- phase A: x = An2 @ X[b]. Wave's c-slice of 32. acc[4][2]=32, bfr[2][2]=16.
    f32x4 acc_a[4][2];
    {
        const int c0 = wid * 32;
        bf16x8 bfr[2][2];
        #pragma unroll
        for (int kt = 0; kt < 2; ++kt)
            #pragma unroll
            for (int nt = 0; nt < 2; ++nt) {
                int row = c0 + nt * 16 + (lane & 15);
                int byte = row * 128 + (kt * 32 + 8 * (lane >> 4)) * 2;
                byte ^= (row & 7) << 4;
                bfr[kt][nt] = *(const bf16x8*)((const char*)xbuf + byte);
            }
        #pragma unroll
        for (int mt = 0; mt < 4; ++mt) {
            #pragma unroll
            for (int nt = 0; nt < 2; ++nt) acc_a[mt][nt] = (f32x4)0.f;
            #pragma unroll
            for (int kt = 0; kt < 2; ++kt) {
                bf16x8 afr = *(const bf16x8*)&an2lds[((mt * 2 + kt) * 64 + lane) * 8];
                #pragma unroll
                for (int nt = 0; nt < 2; ++nt)
                    acc_a[mt][nt] = __builtin_amdgcn_mfma_f32_16x16x32_bf16(afr, bfr[kt][nt], acc_a[mt][nt], 0, 0, 0);
            }
        }
    }
    __syncthreads();  // all waves done READING xbuf (X^T)

    // ---- write xs over xbuf (wave's 32 cols). C layout (verified): col=lane&15, row=(lane>>4)*4+r.
    {
        const int c0 = wid * 32;
        #pragma unroll
        for (int mt = 0; mt < 4; ++mt)
            #pragma unroll
            for (int nt = 0; nt < 2; ++nt)
                #pragma unroll
                for (int r = 0; r < 4; ++r) {
                    int row = mt * 16 + (lane >> 4) * 4 + r;       // n
                    int col = c0 + nt * 16 + (lane & 15);          // c
                    int byte = row * 512 + col * 2;
                    byte ^= (row & 7) << 4;
                    *(short*)((char*)xbuf + byte) = f2bf(acc_a[mt][nt][r]);
                }
    }
    __syncthreads();

    // ---- phase B: pooled = sum_n relu(x @ convW + b). Wave owns j-slice of 64,
    // two sequential 32n passes (acc[2][4]=32); psum carries the pooled sums across passes.
    {
        const int j0 = wid * 64;
        float psum[4] = {0.f, 0.f, 0.f, 0.f};
        #pragma unroll 1
        for (int nh = 0; nh < 2; ++nh) {
            f32x4 acc[2][4];
            #pragma unroll
            for (int mt = 0; mt < 2; ++mt)
                #pragma unroll
                for (int nt = 0; nt < 4; ++nt) acc[mt][nt] = (f32x4)0.f;
            #pragma unroll
            for (int kt = 0; kt < 8; ++kt) {
                bf16x8 bw[4];
                #pragma unroll
                for (int nt = 0; nt < 4; ++nt) {
                    int ntg = (j0 >> 4) + nt;
                    bw[nt] = *(const bf16x8*)&wf[((kt * 32 + ntg) * 64 + lane) * 8];
                }
                #pragma unroll
                for (int mt = 0; mt < 2; ++mt) {
                    int n = nh * 32 + mt * 16 + (lane & 15);
                    int byte = n * 512 + (kt * 32 + 8 * (lane >> 4)) * 2;
                    byte ^= (n & 7) << 4;
                    bf16x8 ax = *(const bf16x8*)((const char*)xbuf + byte);
                    #pragma unroll
                    for (int nt = 0; nt < 4; ++nt)
                        acc[mt][nt] = __builtin_amdgcn_mfma_f32_16x16x32_bf16(ax, bw[nt], acc[mt][nt], 0, 0, 0);
                }
            }
            #pragma unroll
            for (int nt = 0; nt < 4; ++nt) {
                float bj = convb[j0 + nt * 16 + (lane & 15)];
                float s = 0.f;
                #pragma unroll
                for (int mt = 0; mt < 2; ++mt)
                    #pragma unroll
                    for (int r = 0; r < 4; ++r)
                        s += fmaxf(acc[mt][nt][r] + bj, 0.f);
                psum[nt] += s;
            }
        }
        #pragma unroll
        for (int nt = 0; nt < 4; ++nt) {
            float s = psum[nt];
            s += __shfl_xor(s, 16);
            s += __shfl_xor(s, 32);
            if (lane < 16) pooled[j0 + nt * 16 + (lane & 15)] = s;
        }
    }
    __syncthreads();

    // ---- fc (512 -> 2) + log_softmax, one wave
    if (wid == 0) {
        float p0 = 0.f, p1 = 0.f;
        #pragma unroll
        for (int j = lane; j < 512; j += 64) {
            float pv = pooled[j];
            p0 += pv * fcW[j];
            p1 += pv * fcW[512 + j];
        }
        #pragma unroll
        for (int d = 1; d < 64; d <<= 1) {
            p0 += __shfl_xor(p0, d);
            p1 += __shfl_xor(p1, d);
        }
        if (lane == 0) {
            float l0 = p0 + fcb[0], l1 = p1 + fcb[1];
            float m = fmaxf(l0, l1);
            float lse = m + logf(expf(l0 - m) + expf(l1 - m));
            out[b * 2 + 0] = l0 - lse;
            out[b * 2 + 1] = l1 - lse;
        }
    }
}

extern "C" void kernel_launch(void* const* d_in, const int* in_sizes, int n_in,
                              void* d_out, int out_size, void* d_ws, size_t ws_size,
                              hipStream_t stream) {
    const float* X     = (const float*)d_in[0];
    const float* tril  = (const float*)d_in[1];
    const float* convW = (const float*)d_in[2];
    const float* convb = (const float*)d_in[3];
    const float* fcW   = (const float*)d_in[4];
    const float* fcb   = (const float*)d_in[5];
    float* out = (float*)d_out;
    short* an2f = (short*)d_ws;          // 4096 bf16 = 8KB
    short* wf   = an2f + 4096;           // 131072 bf16 = 256KB
    prep_an2<<<dim3(1), dim3(256), 0, stream>>>(tril, an2f);
    prep_wf<<<dim3(512), dim3(256), 0, stream>>>(convW, wf);
    rgnn_main<<<dim3(2048), dim3(512), 0, stream>>>(X, an2f, wf, convb, fcW, fcb, out);
}

// Round 11
// 205.339 us; speedup vs baseline: 1.0323x; 1.0323x over previous
//
#include <hip/hip_runtime.h>

typedef float f32x4 __attribute__((ext_vector_type(4)));
typedef short bf16x8 __attribute__((ext_vector_type(8)));

__device__ __forceinline__ short f2bf(float x) {
    unsigned u = __float_as_uint(x);
    unsigned r = (u + 0x7FFFu + ((u >> 16) & 1u)) >> 16;  // RNE
    return (short)r;
}

// async global->LDS, 16B per lane; lds base wave-uniform (HW adds lane*16)
__device__ __forceinline__ void gld_lds16(const void* g, void* l) {
    __builtin_amdgcn_global_load_lds(
        (const __attribute__((address_space(1))) unsigned int*)g,
        (__attribute__((address_space(3))) unsigned int*)l, 16, 0, 0);
}

// ---------------- prep 1: An2 = (D^-1/2 (W+I) D^-1/2)^2, written as bf16 A-fragments ----------------
__global__ void prep_an2(const float* __restrict__ tril, short* __restrict__ an2f) {
    __shared__ float Wm[64][64];
    __shared__ float An[64][64];
    __shared__ float An2[64][64];
    __shared__ float dinv[64];
    const int t = threadIdx.x;  // 256 threads
    for (int e = t; e < 4096; e += 256) {
        int i = e >> 6, j = e & 63;
        int hi = i > j ? i : j, lo = i > j ? j : i;
        Wm[i][j] = tril[hi * (hi + 1) / 2 + lo];  // symmetric rebuild
    }
    __syncthreads();
    if (t < 64) {
        float s = 0.f;
        for (int j = 0; j < 64; ++j) s += fabsf(Wm[t][j]);
        s += 1.0f;
        dinv[t] = (s > 0.f) ? 1.0f / sqrtf(s) : 0.f;
    }
    __syncthreads();
    for (int e = t; e < 4096; e += 256) {
        int i = e >> 6, j = e & 63;
        float a = Wm[i][j] + (i == j ? 1.0f : 0.0f);
        An[i][j] = dinv[i] * a * dinv[j];
    }
    __syncthreads();
    for (int e = t; e < 4096; e += 256) {
        int i = e >> 6, j = e & 63;
        float acc = 0.f;
        for (int m = 0; m < 64; ++m) acc += An[i][m] * An[m][j];
        An2[i][j] = acc;
    }
    __syncthreads();
    // A-fragment order: [mt(4)][kt(2)][lane(64)][e(8)], elem = An2[mt*16+(lane&15)][kt*32+8*(lane>>4)+e]
    for (int o = t; o < 4096; o += 256) {
        int e = o & 7, lane = (o >> 3) & 63, kt = (o >> 9) & 1, mt = o >> 10;
        int m = mt * 16 + (lane & 15);
        int k = kt * 32 + 8 * (lane >> 4) + e;
        an2f[o] = f2bf(An2[m][k]);
    }
}

// ---------------- prep 2: convW -> bf16 B-fragments [kt(8)][nt(32)][lane(64)][e(8)] ----------------
__global__ void prep_wf(const float* __restrict__ convW, short* __restrict__ wf) {
    int o = blockIdx.x * 256 + threadIdx.x;  // 131072 elements
    int e = o & 7, lane = (o >> 3) & 63, nt = (o >> 9) & 31, kt = o >> 14;
    int k = kt * 32 + 8 * (lane >> 4) + e;
    int j = nt * 16 + (lane & 15);
    wf[o] = f2bf(convW[k * 512 + j]);
}

// ---------------- main: per-batch fused hop+conv+pool+fc+log_softmax ----------------
// Occupancy attack, round 11: the transposing stage loop was the arch-VGPR hog that
// made every cap spill (R4/R7/R8/R10: hipcc splits a cap ~50/50 arch/acc). Replace it
// with global_load_lds of X in f32 (R6-verified chunk-swizzle; zero staging regs/VALU),
// build phase-A B-frags transiently from LDS. 512-thr blocks + R10's verified halved
// tiles: arch ~55-60, acc <=32 -> fits (512,4)'s 64/64 split. LDS 74KB (X 64K aliased
// by xs, an2 8K, pooled 2K) -> 2 blocks/CU = 4 waves/SIMD (2x every clean run so far).
__global__ __launch_bounds__(512, 4) void rgnn_main(
    const float* __restrict__ X, const short* __restrict__ an2f,
    const short* __restrict__ wf, const float* __restrict__ convb,
    const float* __restrict__ fcW, const float* __restrict__ fcb,
    float* __restrict__ out)
{
    __shared__ char xmem[65536];     // X[b] f32, chunk-swizzled; first 32KB later = xs bf16
    __shared__ short an2lds[4096];   // 8KB An2 bf16 A-fragments
    __shared__ float pooled[512];
    short* xs = (short*)xmem;        // x = An2@X[b], [n][c] bf16, 512B rows, ^((n&7)<<4) swizzle
    const int b = blockIdx.x;
    const int t = threadIdx.x;
    const int lane = t & 63;
    const int wid = t >> 6;          // 0..7
    const float* Xb = X + (size_t)b * (64 * 256);

    // ---- stage an2 (8KB) + X[b] (64KB f32) via async global_load_lds. Source chunk-swizzle
    // (R6-verified): lds[m*1024+j] = X[m*1024 + (j ^ (((m>>3)&3)<<5))]; the phase-A read
    // XOR ((lane>>4)<<5) composes to identity because (m>>3)&3 == (lane>>4)&3 there.
    gld_lds16((const char*)an2f + (wid * 64 + lane) * 16, (char*)an2lds + wid * 1024);
    {
        const char* XbB = (const char*)Xb;
        #pragma unroll
        for (int i = 0; i < 8; ++i) {
            const int chunk = wid * 8 + i;           // 1KB chunk = one m-row
            const int key = (chunk >> 3) & 3;
            gld_lds16(XbB + chunk * 1024 + ((lane ^ (key << 1)) * 16), xmem + chunk * 1024);
        }
    }
    __syncthreads();  // compiler drains vmcnt before barrier

    // ---- phase A: x = An2 @ X[b]. Wave's c-slice of 32. Build ALL B-frags first
    // (bfr[2][2]=16 regs), barrier (X fully consumed), then MFMA + xs overwrite.
    const int c0a = wid * 32;
    bf16x8 bfr[2][2];
    #pragma unroll
    for (int kt = 0; kt < 2; ++kt)
        #pragma unroll
        for (int nt = 0; nt < 2; ++nt) {
            const int cc = c0a + nt * 16 + (lane & 15);
            #pragma unroll
            for (int e = 0; e < 8; ++e) {
                const int m = kt * 32 + 8 * (lane >> 4) + e;
                const int a = (m * 1024 + cc * 4) ^ ((lane >> 4) << 5);
                bfr[kt][nt][e] = f2bf(*(const float*)(xmem + a));
            }
        }
    __syncthreads();  // all waves done reading X f32 region

    {
        f32x4 acc_a[4][2];
        #pragma unroll
        for (int mt = 0; mt < 4; ++mt) {
            #pragma unroll
            for (int nt = 0; nt < 2; ++nt) acc_a[mt][nt] = (f32x4)0.f;
            #pragma unroll
            for (int kt = 0; kt < 2; ++kt) {
                bf16x8 afr = *(const bf16x8*)&an2lds[((mt * 2 + kt) * 64 + lane) * 8];
                #pragma unroll
                for (int nt = 0; nt < 2; ++nt)
                    acc_a[mt][nt] = __builtin_amdgcn_mfma_f32_16x16x32_bf16(afr, bfr[kt][nt], acc_a[mt][nt], 0, 0, 0);
            }
        }
        // write xs (overwrites consumed X region). C layout (verified): col=lane&15, row=(lane>>4)*4+r.
        #pragma unroll
        for (int mt = 0; mt < 4; ++mt)
            #pragma unroll
            for (int nt = 0; nt < 2; ++nt)
                #pragma unroll
                for (int r = 0; r < 4; ++r) {
                    int n = mt * 16 + (lane >> 4) * 4 + r;
                    int col = c0a + nt * 16 + (lane & 15);
                    int byte = n * 512 + col * 2;
                    byte ^= (n & 7) << 4;
                    *(short*)((char*)xs + byte) = f2bf(acc_a[mt][nt][r]);
                }
    }
    __syncthreads();

    // ---- phase B: pooled = sum_n relu(x @ convW + b). Wave owns j-slice of 64,
    // two sequential 32n passes (acc[2][4]=32 AGPR); psum carries pooled sums.
    {
        const int j0 = wid * 64;
        float psum[4] = {0.f, 0.f, 0.f, 0.f};
        #pragma unroll 1
        for (int nh = 0; nh < 2; ++nh) {
            f32x4 acc[2][4];
            #pragma unroll
            for (int mt = 0; mt < 2; ++mt)
                #pragma unroll
                for (int nt = 0; nt < 4; ++nt) acc[mt][nt] = (f32x4)0.f;
            #pragma unroll
            for (int kt = 0; kt < 8; ++kt) {
                bf16x8 bw[4];
                #pragma unroll
                for (int nt = 0; nt < 4; ++nt) {
                    int ntg = (j0 >> 4) + nt;
                    bw[nt] = *(const bf16x8*)&wf[((kt * 32 + ntg) * 64 + lane) * 8];
                }
                #pragma unroll
                for (int mt = 0; mt < 2; ++mt) {
                    int n = nh * 32 + mt * 16 + (lane & 15);
                    int byte = n * 512 + (kt * 32 + 8 * (lane >> 4)) * 2;
                    byte ^= (n & 7) << 4;
                    bf16x8 ax = *(const bf16x8*)((const char*)xs + byte);
                    #pragma unroll
                    for (int nt = 0; nt < 4; ++nt)
                        acc[mt][nt] = __builtin_amdgcn_mfma_f32_16x16x32_bf16(ax, bw[nt], acc[mt][nt], 0, 0, 0);
                }
            }
            #pragma unroll
            for (int nt = 0; nt < 4; ++nt) {
                float bj = convb[j0 + nt * 16 + (lane & 15)];
                float s = 0.f;
                #pragma unroll
                for (int mt = 0; mt < 2; ++mt)
                    #pragma unroll
                    for (int r = 0; r < 4; ++r)
                        s += fmaxf(acc[mt][nt][r] + bj, 0.f);
                psum[nt] += s;
            }
        }
        #pragma unroll
        for (int nt = 0; nt < 4; ++nt) {
            float s = psum[nt];
            s += __shfl_xor(s, 16);
            s += __shfl_xor(s, 32);
            if (lane < 16) pooled[j0 + nt * 16 + (lane & 15)] = s;
        }
    }
    __syncthreads();

    // ---- fc (512 -> 2) + log_softmax, one wave
    if (wid == 0) {
        float p0 = 0.f, p1 = 0.f;
        #pragma unroll
        for (int j = lane; j < 512; j += 64) {
            float pv = pooled[j];
            p0 += pv * fcW[j];
            p1 += pv * fcW[512 + j];
        }
        #pragma unroll
        for (int d = 1; d < 64; d <<= 1) {
            p0 += __shfl_xor(p0, d);
            p1 += __shfl_xor(p1, d);
        }
        if (lane == 0) {
            float l0 = p0 + fcb[0], l1 = p1 + fcb[1];
            float m = fmaxf(l0, l1);
            float lse = m + logf(expf(l0 - m) + expf(l1 - m));
            out[b * 2 + 0] = l0 - lse;
            out[b * 2 + 1] = l1 - lse;
        }
    }
}

extern "C" void kernel_launch(void* const* d_in, const int* in_sizes, int n_in,
                              void* d_out, int out_size, void* d_ws, size_t ws_size,
                              hipStream_t stream) {
    const float* X     = (const float*)d_in[0];
    const float* tril  = (const float*)d_in[1];
    const float* convW = (const float*)d_in[2];
    const float* convb = (const float*)d_in[3];
    const float* fcW   = (const float*)d_in[4];
    const float* fcb   = (const float*)d_in[5];
    float* out = (float*)d_out;
    short* an2f = (short*)d_ws;          // 4096 bf16 = 8KB
    short* wf   = an2f + 4096;           // 131072 bf16 = 256KB
    prep_an2<<<dim3(1), dim3(256), 0, stream>>>(tril, an2f);
    prep_wf<<<dim3(512), dim3(256), 0, stream>>>(convW, wf);
    rgnn_main<<<dim3(2048), dim3(512), 0, stream>>>(X, an2f, wf, convb, fcW, fcb, out);
}